// Round 1
// baseline (143.473 us; speedup 1.0000x reference)
//
#include <hip/hip_runtime.h>

typedef __attribute__((ext_vector_type(8))) short bf16x8;
typedef __attribute__((ext_vector_type(4))) float f32x4;

__device__ __forceinline__ unsigned short f2bf(float x) {
  // round-to-nearest-even fp32 -> bf16 (data is finite; no NaN path needed)
  unsigned u = __builtin_bit_cast(unsigned, x);
  u += 0x7FFFu + ((u >> 16) & 1u);
  return (unsigned short)(u >> 16);
}

// ---------------------------------------------------------------------------
// prep: codebook fp32->bf16 into ws, e2[k]=|e_k|^2 fp32 into ws, zero loss slot
// grid 32 x 256
// ---------------------------------------------------------------------------
__global__ __launch_bounds__(256) void vq_prep(
    const float* __restrict__ cb, unsigned short* __restrict__ cb_bf,
    float* __restrict__ e2, float* __restrict__ loss_slot)
{
  int tid = blockIdx.x * 256 + threadIdx.x;
  if (tid < 8192) {                       // 32768 floats / 4
    f32x4 v = ((const f32x4*)cb)[tid];
    ushort4 o;
    o.x = f2bf(v[0]); o.y = f2bf(v[1]); o.z = f2bf(v[2]); o.w = f2bf(v[3]);
    ((ushort4*)cb_bf)[tid] = o;
  }
  if (tid < 512) {                        // squared norm of code row (fp32)
    const f32x4* row = (const f32x4*)(cb + tid * 64);
    float s = 0.f;
    #pragma unroll
    for (int i = 0; i < 16; ++i) {
      f32x4 v = row[i];
      s += v[0]*v[0] + v[1]*v[1] + v[2]*v[2] + v[3]*v[3];
    }
    e2[tid] = s;
  }
  if (tid == 0) *loss_slot = 0.f;         // d_out is poisoned each call
}

// ---------------------------------------------------------------------------
// main: per block 128 z-rows x all 512 codes via bf16 MFMA, fused argmin,
// fp32 gather + straight-through output + loss partial.
// grid nrows/128 x 256
// ---------------------------------------------------------------------------
__global__ __launch_bounds__(256) void vq_main(
    const float* __restrict__ z, const float* __restrict__ cb32,
    const unsigned short* __restrict__ cb_bf, const float* __restrict__ e2g,
    float* __restrict__ out, float* __restrict__ loss_slot, float loss_scale)
{
  // 512 codes x 64 bf16, XOR-swizzled at 16B-granule level:
  // granule g of row n stored at g ^ (n & 7)  -> B-frag ds_read_b128 is
  // <=2-way bank aliased (free) instead of 16-way. Exactly 64 KB.
  __shared__ unsigned short lds_cb[512 * 64];

  const int tid = threadIdx.x;

  // ---- stage swizzled bf16 codebook (coalesced uint4 reads) ----
  const uint4* src = (const uint4*)cb_bf;     // 4096 granules of 16 B
  #pragma unroll
  for (int i = 0; i < 16; ++i) {
    int G = tid + i * 256;
    int n = G >> 3, g = G & 7;
    int gs = g ^ (n & 7);
    *(uint4*)(&lds_cb[(n << 6) + (gs << 3)]) = src[G];
  }

  const int lane = tid & 63;
  const int w    = tid >> 6;        // wave 0..3
  const int lc   = lane & 15;       // column lane
  const int lq   = lane >> 4;       // quad
  const int rowbase = blockIdx.x * 128 + w * 32;

  // ---- A fragments: z rows fp32 -> bf16 in-register ----
  // lane reads z[row = base + t*16 + lc][d = lq*8 + s*32 .. +7]
  bf16x8 a[2][2];
  #pragma unroll
  for (int t = 0; t < 2; ++t) {
    const float* zp = z + (size_t)(rowbase + t * 16 + lc) * 64 + lq * 8;
    #pragma unroll
    for (int s = 0; s < 2; ++s) {
      f32x4 v0 = *(const f32x4*)(zp + s * 32);
      f32x4 v1 = *(const f32x4*)(zp + s * 32 + 4);
      bf16x8 f;
      f[0] = (short)f2bf(v0[0]); f[1] = (short)f2bf(v0[1]);
      f[2] = (short)f2bf(v0[2]); f[3] = (short)f2bf(v0[3]);
      f[4] = (short)f2bf(v1[0]); f[5] = (short)f2bf(v1[1]);
      f[6] = (short)f2bf(v1[2]); f[7] = (short)f2bf(v1[3]);
      a[t][s] = f;
    }
  }
  __syncthreads();

  // ---- fused GEMM + argmin over 32 n-tiles of 16 codes ----
  float minv[2][4];
  int   mini[2][4];
  #pragma unroll
  for (int t = 0; t < 2; ++t)
    #pragma unroll
    for (int r = 0; r < 4; ++r) { minv[t][r] = 3.4e38f; mini[t][r] = 0; }

  #pragma unroll 4
  for (int nt = 0; nt < 32; ++nt) {
    int n = nt * 16 + lc;                       // this lane's code id
    int base = n << 6;
    bf16x8 b0 = *(const bf16x8*)(&lds_cb[base + ((lq       ^ (n & 7)) << 3)]);
    bf16x8 b1 = *(const bf16x8*)(&lds_cb[base + (((lq + 4) ^ (n & 7)) << 3)]);
    float ev = e2g[n];
    #pragma unroll
    for (int t = 0; t < 2; ++t) {
      f32x4 c = {0.f, 0.f, 0.f, 0.f};
      c = __builtin_amdgcn_mfma_f32_16x16x32_bf16(a[t][0], b0, c, 0, 0, 0);
      c = __builtin_amdgcn_mfma_f32_16x16x32_bf16(a[t][1], b1, c, 0, 0, 0);
      #pragma unroll
      for (int r = 0; r < 4; ++r) {
        float dist = fmaf(-2.f, c[r], ev);      // |e|^2 - 2 z.e  (drop |z|^2)
        if (dist < minv[t][r]) { minv[t][r] = dist; mini[t][r] = n; }
      }
    }
  }

  // ---- reduce argmin across the 16 column-lanes (first-min tie-break) ----
  #pragma unroll
  for (int m = 1; m <= 8; m <<= 1) {
    #pragma unroll
    for (int t = 0; t < 2; ++t)
      #pragma unroll
      for (int r = 0; r < 4; ++r) {
        float ov = __shfl_xor(minv[t][r], m, 64);
        int   oi = __shfl_xor(mini[t][r], m, 64);
        if (ov < minv[t][r] || (ov == minv[t][r] && oi < mini[t][r])) {
          minv[t][r] = ov; mini[t][r] = oi;
        }
      }
  }

  __syncthreads();                  // all waves done reading lds_cb
  int* idxp = (int*)lds_cb;         // reuse LDS for per-row argmin index
  if (lc == 0) {
    #pragma unroll
    for (int t = 0; t < 2; ++t)
      #pragma unroll
      for (int r = 0; r < 4; ++r)
        idxp[w * 32 + t * 16 + lq * 4 + r] = mini[t][r];
  }
  __syncthreads();

  // ---- gather (fp32 codebook), straight-through output, loss partial ----
  float sq = 0.f;
  const f32x4* z4 = (const f32x4*)(z   + (size_t)blockIdx.x * 128 * 64);
  f32x4*       o4 = (f32x4*)      (out + (size_t)blockIdx.x * 128 * 64);
  const f32x4* c4 = (const f32x4*)cb32;
  #pragma unroll
  for (int i = 0; i < 8; ++i) {
    int f4  = i * 256 + tid;        // 0..2047 float4s of this block
    int row = f4 >> 4, d4 = f4 & 15;
    int idx = idxp[row];
    f32x4 q  = c4[idx * 16 + d4];
    f32x4 zz = z4[f4];
    f32x4 o;
    #pragma unroll
    for (int e = 0; e < 4; ++e) {
      float d = q[e] - zz[e];       // mirrors reference: z + (q - z)
      o[e] = zz[e] + d;
      sq += d * d;
    }
    o4[f4] = o;
  }

  #pragma unroll
  for (int m = 1; m <= 32; m <<= 1) sq += __shfl_xor(sq, m, 64);
  if (lane == 0) atomicAdd(loss_slot, sq * loss_scale);
}

// ---------------------------------------------------------------------------
extern "C" void kernel_launch(void* const* d_in, const int* in_sizes, int n_in,
                              void* d_out, int out_size, void* d_ws, size_t ws_size,
                              hipStream_t stream) {
  const float* z  = (const float*)d_in[0];
  const float* cb = (const float*)d_in[1];
  float* out = (float*)d_out;

  const int Nz    = in_sizes[0];        // 8388608 = 131072 rows * 64
  const int nrows = Nz / 64;            // 131072

  unsigned short* cb_bf = (unsigned short*)d_ws;            // 64 KB
  float* e2 = (float*)((char*)d_ws + 512 * 64 * sizeof(unsigned short));
  float* loss_slot = out + Nz;
  float loss_scale = 1.25f / (float)Nz; // (1 + 0.25) * mean

  vq_prep<<<32, 256, 0, stream>>>(cb, cb_bf, e2, loss_slot);
  vq_main<<<nrows / 128, 256, 0, stream>>>(z, cb, cb_bf, e2, out, loss_slot,
                                           loss_scale);
}